// Round 19
// baseline (138.989 us; speedup 1.0000x reference)
//
#include <hip/hip_runtime.h>
#include <hip/hip_bf16.h>

// ---------------- problem constants ----------------
constexpr int NV = 16384;   // 16*1024 z vectors
constexpr int D  = 128;     // embed dim
constexpr int NE = 8192;    // codebook size
constexpr float DECAY = 0.99f;
constexpr float BETA  = 1.0f;
constexpr float EPS   = 1e-5f;
constexpr float LO_SCALE     = 4096.0f;        // 2^12: keeps f16 lo-part normal
constexpr float INV_LO_SCALE = 1.0f / 4096.0f;

// packed-screen quantization: u = (u32(s*65536 + 98304) << 13) | code
constexpr float QSCALE = 65536.0f;
constexpr float QOFF   = 98304.0f;

// distance-kernel geometry
constexpr int Q = 8;                       // code slices (grid.y) -> 1024 blocks = 4/CU
constexpr int CODES_PER_Q = NE / Q;        // 1024
constexpr int TILE_C = 32;                 // codes per LDS tile (one colfrag)
constexpr int TILES = CODES_PER_Q / TILE_C;// 32
constexpr int BZ = 128;                    // z rows per block (4 waves x 32 rows)
constexpr int NCAND = Q * 2;               // refine candidates per row (16)

// ---------------- ws layout (float units) ----------------
constexpr size_t WS_Z2    = 0;                            // NV x 256 f16 = NV*128 floats
constexpr size_t WS_E2    = WS_Z2 + (size_t)NV * 128;     // NE x 128 f16 (hi only); region NE*128 floats
constexpr size_t WS_EN2   = WS_E2 + (size_t)NE * 128;     // NE (fp32)
constexpr size_t WS_MINI2 = WS_EN2 + NE;                  // NV*NCAND (u32 packed)
// aliases over z2 region (z2 dead once k_dist finishes)
constexpr size_t WS_BINS  = WS_Z2;                        // NE
constexpr size_t WS_ESUM  = WS_BINS + NE;                 // NE*D
constexpr size_t WS_LPART = WS_ESUM + (size_t)NE * D;     // 4096

// ---------------- out layout (float units) ----------------
constexpr size_t OUT_ZQ   = 0;                         // NV*D
constexpr size_t OUT_LOSS = OUT_ZQ + (size_t)NV*D;     // 1
constexpr size_t OUT_IDX  = OUT_LOSS + 1;              // NV
constexpr size_t OUT_EMB  = OUT_IDX + NV;              // NE*D
constexpr size_t OUT_CS   = OUT_EMB + (size_t)NE*D;    // NE
constexpr size_t OUT_EAVG = OUT_CS + NE;               // NE*D

using half8  = __attribute__((ext_vector_type(8))) _Float16;
using half2v = __attribute__((ext_vector_type(2))) _Float16;
using f32x16 = __attribute__((ext_vector_type(16))) float;

__device__ inline float waveReduceSum(float v) {
    #pragma unroll
    for (int o = 32; o > 0; o >>= 1) v += __shfl_xor(v, o, 64);
    return v;
}
__device__ inline unsigned umin32(unsigned a, unsigned b) { return a < b ? a : b; }
__device__ inline unsigned umax32(unsigned a, unsigned b) { return a > b ? a : b; }

// async global->LDS, 16B per lane; LDS dest = wave-uniform base + lane*16 (linear)
__device__ inline void gload_lds16(const void* g, void* s) {
    __builtin_amdgcn_global_load_lds(
        (const __attribute__((address_space(1))) unsigned int*)g,
        (__attribute__((address_space(3))) unsigned int*)s, 16, 0, 0);
}

// ---------- fused prep: z rows (normalize + hi/lo split) and emb rows (hi-only + |e|^2) ----------
__global__ void k_prep(const float* __restrict__ z, const float* __restrict__ emb,
                       _Float16* __restrict__ z2, _Float16* __restrict__ e2h,
                       float* __restrict__ en2) {
    int tid = threadIdx.x;
    int l = tid & 63;
    int g = blockIdx.x * 4 + (tid >> 6);
    bool isZ = g < NV;
    int row = isZ ? g : g - NV;
    const float* src = isZ ? &z[(size_t)row * D] : &emb[(size_t)row * D];

    const float2 v = *reinterpret_cast<const float2*>(&src[l * 2]);
    float s = waveReduceSum(v.x * v.x + v.y * v.y);
    float x0 = v.x, x1 = v.y;
    if (isZ) {
        float inv = 1.0f / fmaxf(sqrtf(s), 1e-12f);
        x0 *= inv; x1 *= inv;
        _Float16 h0 = (_Float16)x0, h1 = (_Float16)x1;
        _Float16 l0 = (_Float16)((x0 - (float)h0) * LO_SCALE);
        _Float16 l1 = (_Float16)((x1 - (float)h1) * LO_SCALE);
        _Float16* zr = &z2[(size_t)row * 256];
        half2v hh = {h0, h1}, lv = {l0, l1};
        *reinterpret_cast<half2v*>(&zr[l * 2])       = hh;
        *reinterpret_cast<half2v*>(&zr[128 + l * 2]) = lv;
    } else {
        if (l == 0) en2[row] = s;   // bitwise = round-1 k_enorm2
        _Float16 h0 = (_Float16)x0, h1 = (_Float16)x1;
        half2v hh = {h0, h1};
        *reinterpret_cast<half2v*>(&e2h[(size_t)row * 128 + l * 2]) = hh;
    }
}

// ---------- MFMA 32x32x16 distance screen (R18 pipeline, Q=8 / TILE_C=32 / 4 blocks/CU) ----------
// 256 thr = 4 waves; wave owns 32 z rows. 32-code tiles (one colfrag each),
// TRIPLE-buffered via global_load_lds, prefetch depth 2, raw s_barrier + counted
// s_waitcnt (T4: newer stage loads stay in flight across barriers; vmcnt(0) only at
// the last tile). Grid = 128 x 8 = 1024 blocks = 4 blocks/CU -> 4 waves/SIMD (the
// occupancy lever: R5-R18 were stuck at 2 because the 512-block grid only SUPPLIED
// 2/CU). LDS 28 KB; VGPR target <=128.
// 2-term screen: dot ~= zh.eh + (zl.eh)/4096 (err ~2e-5; covered by top-2-per-slice +
// fp32 arbiter). 7-op packed-u32 top-2 epilogue (R17/R18-proven numerics).
// C/D: col=lane&31, row=(reg&3)+8*(reg>>2)+4*(lane>>5) (m74/m101-verified).
__global__ __launch_bounds__(256, 2) void k_dist(
        const _Float16* __restrict__ z2, const _Float16* __restrict__ e2h,
        const float* __restrict__ en2, unsigned* __restrict__ minI2) {
    __shared__ _Float16 eb[3][TILE_C * 128];   // 3 x 8 KB
    __shared__ float c0s[CODES_PER_Q];         // 4 KB

    const int tid = threadIdx.x;
    const int w  = tid >> 6;
    const int l  = tid & 63;
    const int cc = l & 31;      // A-row / B-col index (32-wide)
    const int gg = l >> 5;      // k-half group (0..1)
    const int zb = blockIdx.x * BZ;
    const int q  = blockIdx.y;
    const int cbase0 = q * CODES_PER_Q;

    // A fragments: a_h/a_l[kf] = z2[row][kf*16 + gg*8 ..+8] (hi), +128 (lo); kf=0..7
    half8 a_h[8], a_l[8];
    {
        const size_t row = (size_t)(zb + w * 32 + cc);
        #pragma unroll
        for (int kf = 0; kf < 8; ++kf) {
            a_h[kf] = *reinterpret_cast<const half8*>(&z2[row * 256 + kf * 16 + gg * 8]);
            a_l[kf] = *reinterpret_cast<const half8*>(&z2[row * 256 + 128 + kf * 16 + gg * 8]);
        }
    }

    // prequantized constant: c0 = |e|^2 * QSCALE + QOFF
    for (int i = tid; i < CODES_PER_Q; i += 256)
        c0s[i] = fmaf(en2[cbase0 + i], QSCALE, QOFF);

    // drain A/en2 loads + c0s ds_writes so the vmcnt queue = stage loads ONLY,
    // and this wave's c0s writes are complete before the first barrier.
    asm volatile("s_waitcnt vmcnt(0) lgkmcnt(0)" ::: "memory");

    // stage tile t: 512 chunks; wave w load i (i<2) covers chunk (w*2+i)*64 + l;
    // code = c>>4, slot = c&15; global src pre-swizzled slot' = slot ^ (code&7);
    // LDS dest linear (wave-uniform base + lane*16).
    int soff[2];
    #pragma unroll
    for (int i = 0; i < 2; ++i) {
        int c = (w * 2 + i) * 64 + l;
        int code = c >> 4, slot = c & 15;
        soff[i] = code * 256 + ((slot ^ (code & 7)) * 16);
    }
    auto stage = [&](int b, int t) {
        const char* tbase = reinterpret_cast<const char*>(&e2h[(size_t)(cbase0 + t * TILE_C) * 128]);
        #pragma unroll
        for (int i = 0; i < 2; ++i)
            gload_lds16(tbase + soff[i], &eb[b][(size_t)(w * 2 + i) * 512]);
    };

    stage(0, 0);            // 2 outstanding
    stage(1, 1);            // 4 outstanding

    unsigned bU1[16], bU2[16];
    #pragma unroll
    for (int i = 0; i < 16; ++i) { bU1[i] = 0xFFFFFFFFu; bU2[i] = 0xFFFFFFFFu; }

    const int swz = cc & 7;      // read-side XOR (matches staged involution)

    int cur = 0;
    for (int t = 0; t < TILES; ++t) {
        // barrier: all waves done reading buf[(t-1)%3] (= target of stage(t+2));
        // raw s_barrier only - prefetch loads stay in flight across it.
        __builtin_amdgcn_s_barrier();
        if (t + 2 < TILES) {
            int nb = cur + 2; if (nb >= 3) nb -= 3;
            stage(nb, t + 2);                               // 6 outstanding
            asm volatile("s_waitcnt vmcnt(4)" ::: "memory");  // own stage-t landed
        } else if (t + 1 < TILES) {
            asm volatile("s_waitcnt vmcnt(2)" ::: "memory");
        } else {
            asm volatile("s_waitcnt vmcnt(0)" ::: "memory");
        }
        __builtin_amdgcn_sched_barrier(0);

        const char* rbase = reinterpret_cast<const char*>(&eb[cur][0]) + cc * 256;
        half8 b0 = *reinterpret_cast<const half8*>(rbase + (((0 * 2 + gg) ^ swz) * 16));
        half8 b1 = *reinterpret_cast<const half8*>(rbase + (((1 * 2 + gg) ^ swz) * 16));
        half8 b2 = *reinterpret_cast<const half8*>(rbase + (((2 * 2 + gg) ^ swz) * 16));
        half8 b3 = *reinterpret_cast<const half8*>(rbase + (((3 * 2 + gg) ^ swz) * 16));
        half8 b4 = *reinterpret_cast<const half8*>(rbase + (((4 * 2 + gg) ^ swz) * 16));
        half8 b5 = *reinterpret_cast<const half8*>(rbase + (((5 * 2 + gg) ^ swz) * 16));
        half8 b6 = *reinterpret_cast<const half8*>(rbase + (((6 * 2 + gg) ^ swz) * 16));
        half8 b7 = *reinterpret_cast<const half8*>(rbase + (((7 * 2 + gg) ^ swz) * 16));

        f32x16 accA{}, accB{};
        // 2 chains, interleaved (R16-R18-proven numerics); 16 MFMA per tile
        accA = __builtin_amdgcn_mfma_f32_32x32x16_f16(a_h[0], b0, accA, 0, 0, 0);
        accB = __builtin_amdgcn_mfma_f32_32x32x16_f16(a_l[0], b0, accB, 0, 0, 0);
        accA = __builtin_amdgcn_mfma_f32_32x32x16_f16(a_h[1], b1, accA, 0, 0, 0);
        accB = __builtin_amdgcn_mfma_f32_32x32x16_f16(a_l[1], b1, accB, 0, 0, 0);
        accA = __builtin_amdgcn_mfma_f32_32x32x16_f16(a_h[2], b2, accA, 0, 0, 0);
        accB = __builtin_amdgcn_mfma_f32_32x32x16_f16(a_l[2], b2, accB, 0, 0, 0);
        accA = __builtin_amdgcn_mfma_f32_32x32x16_f16(a_h[3], b3, accA, 0, 0, 0);
        accB = __builtin_amdgcn_mfma_f32_32x32x16_f16(a_l[3], b3, accB, 0, 0, 0);
        accA = __builtin_amdgcn_mfma_f32_32x32x16_f16(a_h[4], b4, accA, 0, 0, 0);
        accB = __builtin_amdgcn_mfma_f32_32x32x16_f16(a_l[4], b4, accB, 0, 0, 0);
        accA = __builtin_amdgcn_mfma_f32_32x32x16_f16(a_h[5], b5, accA, 0, 0, 0);
        accB = __builtin_amdgcn_mfma_f32_32x32x16_f16(a_l[5], b5, accB, 0, 0, 0);
        accA = __builtin_amdgcn_mfma_f32_32x32x16_f16(a_h[6], b6, accA, 0, 0, 0);
        accB = __builtin_amdgcn_mfma_f32_32x32x16_f16(a_l[6], b6, accB, 0, 0, 0);
        accA = __builtin_amdgcn_mfma_f32_32x32x16_f16(a_h[7], b7, accA, 0, 0, 0);
        accB = __builtin_amdgcn_mfma_f32_32x32x16_f16(a_l[7], b7, accB, 0, 0, 0);

        const unsigned code = (unsigned)(cbase0 + t * TILE_C + cc);
        const float c0 = c0s[t * TILE_C + cc];
        #pragma unroll
        for (int r = 0; r < 16; ++r) {
            // 7-op insert: fma, fma, cvt, lshl_or, max, min, min
            float tq = fmaf(-2.0f * QSCALE, accA[r],
                            fmaf(-2.0f * QSCALE * INV_LO_SCALE, accB[r], c0));
            unsigned u = ((unsigned)tq << 13) | code;
            unsigned m1 = bU1[r];
            bU2[r] = umin32(umax32(u, m1), bU2[r]);   // second-min (med3 pattern)
            bU1[r] = umin32(u, m1);
        }
        ++cur; if (cur >= 3) cur -= 3;
    }

    // cross-lane top-2 merge over the 32 cc lanes (disjoint code sets; u unique)
    #pragma unroll
    for (int r = 0; r < 16; ++r) {
        unsigned u1 = bU1[r], u2 = bU2[r];
        #pragma unroll
        for (int m = 1; m < 32; m <<= 1) {
            unsigned o1 = (unsigned)__shfl_xor((int)u1, m, 64);
            unsigned o2 = (unsigned)__shfl_xor((int)u2, m, 64);
            unsigned hi = umax32(u1, o1);
            u1 = umin32(u1, o1);
            u2 = umin32(umin32(u2, o2), hi);
        }
        if (cc == 0) {
            // C/D: row = (r&3) + 8*(r>>2) + 4*gg
            int zrow = zb + w * 32 + (r & 3) + 8 * (r >> 2) + 4 * gg;
            size_t o = ((size_t)zrow * Q + q) * 2;
            minI2[o] = u1; minI2[o + 1] = u2;
        }
    }
}

// ---------- fp32-replica refine over 16 candidates (LDS-staged rows) + gather + loss + segsums ----------
__global__ void k_gather(const float* __restrict__ z, const float* __restrict__ emb,
                         const float* __restrict__ en2, const unsigned* __restrict__ minI2,
                         float* __restrict__ outZq, float* __restrict__ outIdx,
                         float* __restrict__ bins, float* __restrict__ esum,
                         float* __restrict__ lossPart) {
    __shared__ float zsh[4][128];
    __shared__ float ecs[4][NCAND][132];    // +4 pad: chain-lanes hit distinct banks
    int tid = threadIdx.x;
    int wave = tid >> 6, lane = tid & 63;
    int zr = blockIdx.x * 4 + wave;

    // zn exactly as round-1 k_norm_z (fp32 butterfly, same ops)
    const float2 zv = *reinterpret_cast<const float2*>(&z[(size_t)zr * D + lane * 2]);
    float s = waveReduceSum(zv.x * zv.x + zv.y * zv.y);
    float inv = 1.0f / fmaxf(sqrtf(s), 1e-12f);
    float znx = zv.x * inv, zny = zv.y * inv;
    zsh[wave][lane * 2]     = znx;
    zsh[wave][lane * 2 + 1] = zny;

    // candidate codes + coalesced staging of the 16 rows (values bit-identical;
    // the arbiter chain below is unchanged). All per-wave LDS: no block barrier.
    int ci = 0x7fffffff;
    if (lane < NCAND) ci = (int)(minI2[(size_t)zr * NCAND + lane] & 8191u);
    #pragma unroll
    for (int c = 0; c < NCAND; ++c) {
        int cc_ = __shfl(ci, c, 64);
        const float2 ev = *reinterpret_cast<const float2*>(&emb[(size_t)cc_ * D + lane * 2]);
        ecs[wave][c][lane * 2]     = ev.x;
        ecs[wave][c][lane * 2 + 1] = ev.y;
    }

    // 16 lanes re-score with the proven fp32 arbiter arithmetic:
    // sequential fmaf chain k=0..127, then s = fmaf(-2, dot, en2[c]).
    float cv = 3.4e38f;
    if (lane < NCAND) {
        float dot = 0.0f;
        #pragma unroll 8
        for (int k = 0; k < 128; ++k) dot = fmaf(zsh[wave][k], ecs[wave][lane][k], dot);
        cv = fmaf(-2.0f, dot, en2[ci]);
    }
    float bv = cv; int bi = ci;
    #pragma unroll
    for (int m = 1; m < NCAND; m <<= 1) {
        float ov = __shfl_xor(bv, m, 64);
        int   oi = __shfl_xor(bi, m, 64);
        if (ov < bv || (ov == bv && oi < bi)) { bv = ov; bi = oi; }
    }
    bi = __shfl(bi, 0, 64);    // broadcast winner to all 64 lanes
    if (lane == 0) outIdx[zr] = (float)bi;

    float2 e = *reinterpret_cast<const float2*>(&emb[(size_t)bi * D + lane * 2]);
    *reinterpret_cast<float2*>(&outZq[(size_t)zr * D + lane * 2]) = e;

    float dx = e.x - znx, dy = e.y - zny;
    float ls = waveReduceSum(dx * dx + dy * dy);

    if (lane == 0) atomicAdd(&bins[bi], 1.0f);
    atomicAdd(&esum[(size_t)bi * D + lane * 2 + 0], znx);
    atomicAdd(&esum[(size_t)bi * D + lane * 2 + 1], zny);

    __shared__ float part[4];
    if (lane == 0) part[wave] = ls;
    __syncthreads();
    if (tid == 0) lossPart[blockIdx.x] = (part[0] + part[1]) + (part[2] + part[3]);
}

// ---------- per-code EMA update + renormalize; block 0 also reduces the loss ----------
__global__ void k_codebook(const float* __restrict__ emb, const float* __restrict__ csz,
                           const float* __restrict__ eavg, const float* __restrict__ bins,
                           const float* __restrict__ esum, const float* __restrict__ lossPart,
                           float* __restrict__ outEmb, float* __restrict__ outCs,
                           float* __restrict__ outEavg, float* __restrict__ outLoss) {
    int tid = threadIdx.x;
    int wave = tid >> 6, lane = tid & 63;
    int n = blockIdx.x * 4 + wave;

    if (blockIdx.x == 0) {               // fold former k_loss here (block-uniform branch)
        float s = 0.0f;
        for (int i = tid; i < 4096; i += 256) s += lossPart[i];
        s = waveReduceSum(s);
        __shared__ float p[4];
        if ((tid & 63) == 0) p[tid >> 6] = s;
        __syncthreads();
        if (tid == 0) outLoss[0] = BETA * ((p[0] + p[1]) + (p[2] + p[3])) / (float)((size_t)NV * D);
    }

    float b = bins[n];
    if (lane == 0) outCs[n] = csz[n] * DECAY + (1.0f - DECAY) * b;

    float2 es = *reinterpret_cast<const float2*>(&esum[(size_t)n * D + lane * 2]);
    float invb = 1.0f / (b + EPS);
    float mx = es.x * invb, my = es.y * invb;
    float ss = waveReduceSum(mx * mx + my * my);
    float invn = 1.0f / fmaxf(sqrtf(ss), 1e-12f);

    float2 er = *reinterpret_cast<const float2*>(&emb[(size_t)n * D + lane * 2]);
    float enx = (b == 0.0f) ? er.x : mx * invn;
    float eny = (b == 0.0f) ? er.y : my * invn;

    float2 ea = *reinterpret_cast<const float2*>(&eavg[(size_t)n * D + lane * 2]);
    float nax = ea.x * DECAY + (1.0f - DECAY) * enx;
    float nay = ea.y * DECAY + (1.0f - DECAY) * eny;
    float2 no; no.x = nax; no.y = nay;
    *reinterpret_cast<float2*>(&outEavg[(size_t)n * D + lane * 2]) = no;

    float ss2 = waveReduceSum(nax * nax + nay * nay);
    float inv2 = 1.0f / fmaxf(sqrtf(ss2), 1e-12f);
    float2 ne; ne.x = nax * inv2; ne.y = nay * inv2;
    *reinterpret_cast<float2*>(&outEmb[(size_t)n * D + lane * 2]) = ne;
}

extern "C" void kernel_launch(void* const* d_in, const int* in_sizes, int n_in,
                              void* d_out, int out_size, void* d_ws, size_t ws_size,
                              hipStream_t stream) {
    (void)in_sizes; (void)n_in; (void)out_size; (void)ws_size;
    const float* z    = (const float*)d_in[0];
    const float* emb  = (const float*)d_in[1];
    const float* csz  = (const float*)d_in[2];
    const float* eavg = (const float*)d_in[3];
    float* out = (float*)d_out;
    float* ws  = (float*)d_ws;

    _Float16* z2   = (_Float16*)(ws + WS_Z2);
    _Float16* e2h  = (_Float16*)(ws + WS_E2);
    float*    en2  = ws + WS_EN2;
    unsigned* minI2 = (unsigned*)(ws + WS_MINI2);
    float*  bins   = ws + WS_BINS;
    float*  esum   = ws + WS_ESUM;
    float*  lpart  = ws + WS_LPART;

    k_prep<<<(NV + NE) / 4, 256, 0, stream>>>(z, emb, z2, e2h, en2);
    k_dist<<<dim3(NV / BZ, Q), 256, 0, stream>>>(z2, e2h, en2, minI2);
    // bins+esum zeroing must follow k_dist (they alias the z2 region)
    hipMemsetAsync(bins, 0, ((size_t)NE + (size_t)NE * D) * sizeof(float), stream);
    k_gather<<<NV / 4, 256, 0, stream>>>(z, emb, en2, minI2,
                                         out + OUT_ZQ, out + OUT_IDX, bins, esum, lpart);
    k_codebook<<<NE / 4, 256, 0, stream>>>(emb, csz, eavg, bins, esum, lpart,
                                           out + OUT_EMB, out + OUT_CS, out + OUT_EAVG,
                                           out + OUT_LOSS);
}

// Round 20
// 124.744 us; speedup vs baseline: 1.1142x; 1.1142x over previous
//
#include <hip/hip_runtime.h>
#include <hip/hip_bf16.h>

// ---------------- problem constants ----------------
constexpr int NV = 16384;   // 16*1024 z vectors
constexpr int D  = 128;     // embed dim
constexpr int NE = 8192;    // codebook size
constexpr float DECAY = 0.99f;
constexpr float BETA  = 1.0f;
constexpr float EPS   = 1e-5f;

// packed-screen quantization: u = (u32(s*65536 + 98304) << 13) | code
constexpr float QSCALE = 65536.0f;
constexpr float QOFF   = 98304.0f;

// distance-kernel geometry
constexpr int Q = 4;                       // code slices (grid.y)
constexpr int CODES_PER_Q = NE / Q;        // 2048
constexpr int TILE_C = 64;                 // codes per block-shared LDS tile
constexpr int TILES = CODES_PER_Q / TILE_C;// 32
constexpr int BZ = 128;                    // z rows per block (4 waves x 32 rows)
constexpr int NCAND = Q * 2;               // refine candidates per row (8)

// ---------------- ws layout (float units) ----------------
constexpr size_t WS_Z2    = 0;                            // NV x 256 f16 = NV*128 floats
constexpr size_t WS_E2    = WS_Z2 + (size_t)NV * 128;     // NE x 128 f16 (hi only); region NE*128 floats
constexpr size_t WS_EN2   = WS_E2 + (size_t)NE * 128;     // NE (fp32)
constexpr size_t WS_MINI2 = WS_EN2 + NE;                  // NV*NCAND (u32 packed)
// aliases over z2 region (z2 dead once k_dist finishes)
constexpr size_t WS_BINS  = WS_Z2;                        // NE
constexpr size_t WS_ESUM  = WS_BINS + NE;                 // NE*D
constexpr size_t WS_LPART = WS_ESUM + (size_t)NE * D;     // 4096

// ---------------- out layout (float units) ----------------
constexpr size_t OUT_ZQ   = 0;                         // NV*D
constexpr size_t OUT_LOSS = OUT_ZQ + (size_t)NV*D;     // 1
constexpr size_t OUT_IDX  = OUT_LOSS + 1;              // NV
constexpr size_t OUT_EMB  = OUT_IDX + NV;              // NE*D
constexpr size_t OUT_CS   = OUT_EMB + (size_t)NE*D;    // NE
constexpr size_t OUT_EAVG = OUT_CS + NE;               // NE*D

using half8  = __attribute__((ext_vector_type(8))) _Float16;
using half2v = __attribute__((ext_vector_type(2))) _Float16;
using f32x16 = __attribute__((ext_vector_type(16))) float;

__device__ inline float waveReduceSum(float v) {
    #pragma unroll
    for (int o = 32; o > 0; o >>= 1) v += __shfl_xor(v, o, 64);
    return v;
}
__device__ inline unsigned umin32(unsigned a, unsigned b) { return a < b ? a : b; }
__device__ inline unsigned umax32(unsigned a, unsigned b) { return a > b ? a : b; }

// async global->LDS, 16B per lane; LDS dest = wave-uniform base + lane*16 (linear)
__device__ inline void gload_lds16(const void* g, void* s) {
    __builtin_amdgcn_global_load_lds(
        (const __attribute__((address_space(1))) unsigned int*)g,
        (__attribute__((address_space(3))) unsigned int*)s, 16, 0, 0);
}

// ---------- fused prep: z rows (normalize + hi/lo split) and emb rows (hi-only + |e|^2) ----------
// z_lo stored UNSCALED (f16 of the residual; subnormal quantum 6e-8 -> dot err ~3e-7,
// far under the 2e-5 screen budget). Lets k_dist accumulate hi and lo into the SAME
// MFMA chains with no 1/4096 rescale.
__global__ void k_prep(const float* __restrict__ z, const float* __restrict__ emb,
                       _Float16* __restrict__ z2, _Float16* __restrict__ e2h,
                       float* __restrict__ en2) {
    int tid = threadIdx.x;
    int l = tid & 63;
    int g = blockIdx.x * 4 + (tid >> 6);
    bool isZ = g < NV;
    int row = isZ ? g : g - NV;
    const float* src = isZ ? &z[(size_t)row * D] : &emb[(size_t)row * D];

    const float2 v = *reinterpret_cast<const float2*>(&src[l * 2]);
    float s = waveReduceSum(v.x * v.x + v.y * v.y);
    float x0 = v.x, x1 = v.y;
    if (isZ) {
        float inv = 1.0f / fmaxf(sqrtf(s), 1e-12f);
        x0 *= inv; x1 *= inv;
        _Float16 h0 = (_Float16)x0, h1 = (_Float16)x1;
        _Float16 l0 = (_Float16)(x0 - (float)h0);   // unscaled residual
        _Float16 l1 = (_Float16)(x1 - (float)h1);
        _Float16* zr = &z2[(size_t)row * 256];
        half2v hh = {h0, h1}, lv = {l0, l1};
        *reinterpret_cast<half2v*>(&zr[l * 2])       = hh;
        *reinterpret_cast<half2v*>(&zr[128 + l * 2]) = lv;
    } else {
        if (l == 0) en2[row] = s;   // bitwise = round-1 k_enorm2
        _Float16 h0 = (_Float16)x0, h1 = (_Float16)x1;
        half2v hh = {h0, h1};
        *reinterpret_cast<half2v*>(&e2h[(size_t)row * 128 + l * 2]) = hh;
    }
}

// ---------- MFMA 32x32x16 distance screen (R18 pipeline + k-major conflict-free LDS) ----------
// 256 thr = 4 waves; wave owns 32 z rows. 64-code tiles, TRIPLE-buffered via
// global_load_lds, prefetch depth 2, raw s_barrier + counted s_waitcnt (T4).
// LDS layout K-MAJOR (R9-proven, 0 bank conflicts): chunk = slot*64 + code, so a
// wave's 64-lane b128 read = two contiguous 512 B segments (8 lanes per 128 B bank
// wrap = perfect banking) and all 8 reads use compile-time immediate offsets
// (kk*2048) off one per-lane base -> zero per-read address VALU (no XOR).
// Screen: dot ~= zh.eh + zl.eh (zl unscaled residual; err ~2e-5 from the dropped
// z.e_lo term; covered by top-2-per-slice + fp32 arbiter). Epilogue 7 ops:
// tq = fma(-2Q,acc1,c0); tq = fma(-2Q,acc2,tq); cvt; lshl_or; max; min; min.
// C/D: col=lane&31, row=(reg&3)+8*(reg>>2)+4*(lane>>5) (m74/m101-verified).
__global__ __launch_bounds__(256, 2) void k_dist(
        const _Float16* __restrict__ z2, const _Float16* __restrict__ e2h,
        const float* __restrict__ en2, unsigned* __restrict__ minI2) {
    __shared__ _Float16 eb[3][TILE_C * 128];   // 3 x 16 KB
    __shared__ float c0s[CODES_PER_Q];         // 8 KB

    const int tid = threadIdx.x;
    const int w  = tid >> 6;
    const int l  = tid & 63;
    const int cc = l & 31;      // A-row / B-col index (32-wide)
    const int gg = l >> 5;      // k-half group (0..1)
    const int zb = blockIdx.x * BZ;
    const int q  = blockIdx.y;
    const int cbase0 = q * CODES_PER_Q;

    // A fragments: a_h/a_l[kf] = z2[row][kf*16 + gg*8 ..+8] (hi), +128 (lo); kf=0..7
    half8 a_h[8], a_l[8];
    {
        const size_t row = (size_t)(zb + w * 32 + cc);
        #pragma unroll
        for (int kf = 0; kf < 8; ++kf) {
            a_h[kf] = *reinterpret_cast<const half8*>(&z2[row * 256 + kf * 16 + gg * 8]);
            a_l[kf] = *reinterpret_cast<const half8*>(&z2[row * 256 + 128 + kf * 16 + gg * 8]);
        }
    }

    // prequantized constant: c0 = |e|^2 * QSCALE + QOFF
    for (int i = tid; i < CODES_PER_Q; i += 256)
        c0s[i] = fmaf(en2[cbase0 + i], QSCALE, QOFF);

    // drain A/en2 loads + c0s ds_writes so the vmcnt queue = stage loads ONLY,
    // and this wave's c0s writes are complete before the first barrier.
    asm volatile("s_waitcnt vmcnt(0) lgkmcnt(0)" ::: "memory");

    // stage tile t: 1024 chunks, chunk c = slot*64 + code (k-major);
    // global src byte = code*256 + slot*16 = (c&63)*256 + (c>>6)*16; LDS dest linear.
    int soff[4];
    #pragma unroll
    for (int i = 0; i < 4; ++i) {
        int c = (w * 4 + i) * 64 + l;
        soff[i] = (c & 63) * 256 + (c >> 6) * 16;
    }
    auto stage = [&](int b, int t) {
        const char* tbase = reinterpret_cast<const char*>(&e2h[(size_t)(cbase0 + t * TILE_C) * 128]);
        #pragma unroll
        for (int i = 0; i < 4; ++i)
            gload_lds16(tbase + soff[i], &eb[b][(size_t)(w * 4 + i) * 512]);
    };

    stage(0, 0);            // 4 outstanding
    stage(1, 1);            // 8 outstanding

    unsigned bU1[16], bU2[16];
    #pragma unroll
    for (int i = 0; i < 16; ++i) { bU1[i] = 0xFFFFFFFFu; bU2[i] = 0xFFFFFFFFu; }

    int cur = 0;
    for (int t = 0; t < TILES; ++t) {
        // barrier: all waves done reading buf[(t-1)%3] (= target of stage(t+2));
        // raw s_barrier only - prefetch loads stay in flight across it.
        __builtin_amdgcn_s_barrier();
        if (t + 2 < TILES) {
            int nb = cur + 2; if (nb >= 3) nb -= 3;
            stage(nb, t + 2);                               // 12 outstanding
            asm volatile("s_waitcnt vmcnt(8)" ::: "memory");  // own stage-t landed
        } else if (t + 1 < TILES) {
            asm volatile("s_waitcnt vmcnt(4)" ::: "memory");
        } else {
            asm volatile("s_waitcnt vmcnt(0)" ::: "memory");
        }
        __builtin_amdgcn_sched_barrier(0);

        #pragma unroll
        for (int n = 0; n < 2; ++n) {          // colfrag: 32 codes each
            // k-major: fragment for (code, slot=kk*2+gg) at byte (kk*2+gg)*1024 + code*16
            const char* rb = reinterpret_cast<const char*>(&eb[cur][0])
                             + gg * 1024 + (n * 32 + cc) * 16;
            half8 b0 = *reinterpret_cast<const half8*>(rb + 0 * 2048);
            half8 b1 = *reinterpret_cast<const half8*>(rb + 1 * 2048);
            half8 b2 = *reinterpret_cast<const half8*>(rb + 2 * 2048);
            half8 b3 = *reinterpret_cast<const half8*>(rb + 3 * 2048);
            half8 b4 = *reinterpret_cast<const half8*>(rb + 4 * 2048);
            half8 b5 = *reinterpret_cast<const half8*>(rb + 5 * 2048);
            half8 b6 = *reinterpret_cast<const half8*>(rb + 6 * 2048);
            half8 b7 = *reinterpret_cast<const half8*>(rb + 7 * 2048);

            f32x16 acc1{}, acc2{};
            // 2 chains (kf 0-3 -> acc1, kf 4-7 -> acc2), hi+lo into the same chain;
            // alternating issue keeps reuse distance 2 (R16-R18-proven cadence).
            acc1 = __builtin_amdgcn_mfma_f32_32x32x16_f16(a_h[0], b0, acc1, 0, 0, 0);
            acc2 = __builtin_amdgcn_mfma_f32_32x32x16_f16(a_h[4], b4, acc2, 0, 0, 0);
            acc1 = __builtin_amdgcn_mfma_f32_32x32x16_f16(a_l[0], b0, acc1, 0, 0, 0);
            acc2 = __builtin_amdgcn_mfma_f32_32x32x16_f16(a_l[4], b4, acc2, 0, 0, 0);
            acc1 = __builtin_amdgcn_mfma_f32_32x32x16_f16(a_h[1], b1, acc1, 0, 0, 0);
            acc2 = __builtin_amdgcn_mfma_f32_32x32x16_f16(a_h[5], b5, acc2, 0, 0, 0);
            acc1 = __builtin_amdgcn_mfma_f32_32x32x16_f16(a_l[1], b1, acc1, 0, 0, 0);
            acc2 = __builtin_amdgcn_mfma_f32_32x32x16_f16(a_l[5], b5, acc2, 0, 0, 0);
            acc1 = __builtin_amdgcn_mfma_f32_32x32x16_f16(a_h[2], b2, acc1, 0, 0, 0);
            acc2 = __builtin_amdgcn_mfma_f32_32x32x16_f16(a_h[6], b6, acc2, 0, 0, 0);
            acc1 = __builtin_amdgcn_mfma_f32_32x32x16_f16(a_l[2], b2, acc1, 0, 0, 0);
            acc2 = __builtin_amdgcn_mfma_f32_32x32x16_f16(a_l[6], b6, acc2, 0, 0, 0);
            acc1 = __builtin_amdgcn_mfma_f32_32x32x16_f16(a_h[3], b3, acc1, 0, 0, 0);
            acc2 = __builtin_amdgcn_mfma_f32_32x32x16_f16(a_h[7], b7, acc2, 0, 0, 0);
            acc1 = __builtin_amdgcn_mfma_f32_32x32x16_f16(a_l[3], b3, acc1, 0, 0, 0);
            acc2 = __builtin_amdgcn_mfma_f32_32x32x16_f16(a_l[7], b7, acc2, 0, 0, 0);

            const unsigned code = (unsigned)(cbase0 + t * TILE_C + n * 32 + cc);
            const float c0 = c0s[t * TILE_C + n * 32 + cc];
            #pragma unroll
            for (int r = 0; r < 16; ++r) {
                // 7-op insert: fma, fma, cvt, lshl_or, max, min, min
                float tq = fmaf(-2.0f * QSCALE, acc1[r], c0);
                tq = fmaf(-2.0f * QSCALE, acc2[r], tq);
                unsigned u = ((unsigned)tq << 13) | code;
                unsigned m1 = bU1[r];
                bU2[r] = umin32(umax32(u, m1), bU2[r]);   // second-min (med3 pattern)
                bU1[r] = umin32(u, m1);
            }
        }
        ++cur; if (cur >= 3) cur -= 3;
    }

    // cross-lane top-2 merge over the 32 cc lanes (disjoint code sets; u unique)
    #pragma unroll
    for (int r = 0; r < 16; ++r) {
        unsigned u1 = bU1[r], u2 = bU2[r];
        #pragma unroll
        for (int m = 1; m < 32; m <<= 1) {
            unsigned o1 = (unsigned)__shfl_xor((int)u1, m, 64);
            unsigned o2 = (unsigned)__shfl_xor((int)u2, m, 64);
            unsigned hi = umax32(u1, o1);
            u1 = umin32(u1, o1);
            u2 = umin32(umin32(u2, o2), hi);
        }
        if (cc == 0) {
            // C/D: row = (r&3) + 8*(r>>2) + 4*gg
            int zrow = zb + w * 32 + (r & 3) + 8 * (r >> 2) + 4 * gg;
            size_t o = ((size_t)zrow * Q + q) * 2;
            minI2[o] = u1; minI2[o + 1] = u2;
        }
    }
}

// ---------- fp32-replica refine over 8 candidates (LDS-staged rows) + gather + loss + segsums ----------
__global__ void k_gather(const float* __restrict__ z, const float* __restrict__ emb,
                         const float* __restrict__ en2, const unsigned* __restrict__ minI2,
                         float* __restrict__ outZq, float* __restrict__ outIdx,
                         float* __restrict__ bins, float* __restrict__ esum,
                         float* __restrict__ lossPart) {
    __shared__ float zsh[4][128];
    __shared__ float ecs[4][NCAND][132];    // +4 pad: chain-lanes hit distinct banks
    int tid = threadIdx.x;
    int wave = tid >> 6, lane = tid & 63;
    int zr = blockIdx.x * 4 + wave;

    // zn exactly as round-1 k_norm_z (fp32 butterfly, same ops)
    const float2 zv = *reinterpret_cast<const float2*>(&z[(size_t)zr * D + lane * 2]);
    float s = waveReduceSum(zv.x * zv.x + zv.y * zv.y);
    float inv = 1.0f / fmaxf(sqrtf(s), 1e-12f);
    float znx = zv.x * inv, zny = zv.y * inv;
    zsh[wave][lane * 2]     = znx;
    zsh[wave][lane * 2 + 1] = zny;

    // candidate codes + coalesced staging of the 8 rows (values bit-identical;
    // the arbiter chain below is unchanged). All per-wave LDS: no block barrier.
    int ci = 0x7fffffff;
    if (lane < NCAND) ci = (int)(minI2[(size_t)zr * NCAND + lane] & 8191u);
    #pragma unroll
    for (int c = 0; c < NCAND; ++c) {
        int cc_ = __shfl(ci, c, 64);
        const float2 ev = *reinterpret_cast<const float2*>(&emb[(size_t)cc_ * D + lane * 2]);
        ecs[wave][c][lane * 2]     = ev.x;
        ecs[wave][c][lane * 2 + 1] = ev.y;
    }

    // 8 lanes re-score with the proven fp32 arbiter arithmetic:
    // sequential fmaf chain k=0..127, then s = fmaf(-2, dot, en2[c]).
    float cv = 3.4e38f;
    if (lane < NCAND) {
        float dot = 0.0f;
        #pragma unroll 8
        for (int k = 0; k < 128; ++k) dot = fmaf(zsh[wave][k], ecs[wave][lane][k], dot);
        cv = fmaf(-2.0f, dot, en2[ci]);
    }
    float bv = cv; int bi = ci;
    #pragma unroll
    for (int m = 1; m < NCAND; m <<= 1) {
        float ov = __shfl_xor(bv, m, 64);
        int   oi = __shfl_xor(bi, m, 64);
        if (ov < bv || (ov == bv && oi < bi)) { bv = ov; bi = oi; }
    }
    bi = __shfl(bi, 0, 64);    // broadcast winner to all 64 lanes
    if (lane == 0) outIdx[zr] = (float)bi;

    float2 e = *reinterpret_cast<const float2*>(&emb[(size_t)bi * D + lane * 2]);
    *reinterpret_cast<float2*>(&outZq[(size_t)zr * D + lane * 2]) = e;

    float dx = e.x - znx, dy = e.y - zny;
    float ls = waveReduceSum(dx * dx + dy * dy);

    if (lane == 0) atomicAdd(&bins[bi], 1.0f);
    atomicAdd(&esum[(size_t)bi * D + lane * 2 + 0], znx);
    atomicAdd(&esum[(size_t)bi * D + lane * 2 + 1], zny);

    __shared__ float part[4];
    if (lane == 0) part[wave] = ls;
    __syncthreads();
    if (tid == 0) lossPart[blockIdx.x] = (part[0] + part[1]) + (part[2] + part[3]);
}

// ---------- per-code EMA update + renormalize; block 0 also reduces the loss ----------
__global__ void k_codebook(const float* __restrict__ emb, const float* __restrict__ csz,
                           const float* __restrict__ eavg, const float* __restrict__ bins,
                           const float* __restrict__ esum, const float* __restrict__ lossPart,
                           float* __restrict__ outEmb, float* __restrict__ outCs,
                           float* __restrict__ outEavg, float* __restrict__ outLoss) {
    int tid = threadIdx.x;
    int wave = tid >> 6, lane = tid & 63;
    int n = blockIdx.x * 4 + wave;

    if (blockIdx.x == 0) {               // fold former k_loss here (block-uniform branch)
        float s = 0.0f;
        for (int i = tid; i < 4096; i += 256) s += lossPart[i];
        s = waveReduceSum(s);
        __shared__ float p[4];
        if ((tid & 63) == 0) p[tid >> 6] = s;
        __syncthreads();
        if (tid == 0) outLoss[0] = BETA * ((p[0] + p[1]) + (p[2] + p[3])) / (float)((size_t)NV * D);
    }

    float b = bins[n];
    if (lane == 0) outCs[n] = csz[n] * DECAY + (1.0f - DECAY) * b;

    float2 es = *reinterpret_cast<const float2*>(&esum[(size_t)n * D + lane * 2]);
    float invb = 1.0f / (b + EPS);
    float mx = es.x * invb, my = es.y * invb;
    float ss = waveReduceSum(mx * mx + my * my);
    float invn = 1.0f / fmaxf(sqrtf(ss), 1e-12f);

    float2 er = *reinterpret_cast<const float2*>(&emb[(size_t)n * D + lane * 2]);
    float enx = (b == 0.0f) ? er.x : mx * invn;
    float eny = (b == 0.0f) ? er.y : my * invn;

    float2 ea = *reinterpret_cast<const float2*>(&eavg[(size_t)n * D + lane * 2]);
    float nax = ea.x * DECAY + (1.0f - DECAY) * enx;
    float nay = ea.y * DECAY + (1.0f - DECAY) * eny;
    float2 no; no.x = nax; no.y = nay;
    *reinterpret_cast<float2*>(&outEavg[(size_t)n * D + lane * 2]) = no;

    float ss2 = waveReduceSum(nax * nax + nay * nay);
    float inv2 = 1.0f / fmaxf(sqrtf(ss2), 1e-12f);
    float2 ne; ne.x = nax * inv2; ne.y = nay * inv2;
    *reinterpret_cast<float2*>(&outEmb[(size_t)n * D + lane * 2]) = ne;
}

extern "C" void kernel_launch(void* const* d_in, const int* in_sizes, int n_in,
                              void* d_out, int out_size, void* d_ws, size_t ws_size,
                              hipStream_t stream) {
    (void)in_sizes; (void)n_in; (void)out_size; (void)ws_size;
    const float* z    = (const float*)d_in[0];
    const float* emb  = (const float*)d_in[1];
    const float* csz  = (const float*)d_in[2];
    const float* eavg = (const float*)d_in[3];
    float* out = (float*)d_out;
    float* ws  = (float*)d_ws;

    _Float16* z2   = (_Float16*)(ws + WS_Z2);
    _Float16* e2h  = (_Float16*)(ws + WS_E2);
    float*    en2  = ws + WS_EN2;
    unsigned* minI2 = (unsigned*)(ws + WS_MINI2);
    float*  bins   = ws + WS_BINS;
    float*  esum   = ws + WS_ESUM;
    float*  lpart  = ws + WS_LPART;

    k_prep<<<(NV + NE) / 4, 256, 0, stream>>>(z, emb, z2, e2h, en2);
    k_dist<<<dim3(NV / BZ, Q), 256, 0, stream>>>(z2, e2h, en2, minI2);
    // bins+esum zeroing must follow k_dist (they alias the z2 region)
    hipMemsetAsync(bins, 0, ((size_t)NE + (size_t)NE * D) * sizeof(float), stream);
    k_gather<<<NV / 4, 256, 0, stream>>>(z, emb, en2, minI2,
                                         out + OUT_ZQ, out + OUT_IDX, bins, esum, lpart);
    k_codebook<<<NE / 4, 256, 0, stream>>>(emb, csz, eavg, bins, esum, lpart,
                                           out + OUT_EMB, out + OUT_CS, out + OUT_EAVG,
                                           out + OUT_LOSS);
}

// Round 21
// 123.602 us; speedup vs baseline: 1.1245x; 1.0092x over previous
//
#include <hip/hip_runtime.h>
#include <hip/hip_bf16.h>

// ---------------- problem constants ----------------
constexpr int NV = 16384;   // 16*1024 z vectors
constexpr int D  = 128;     // embed dim
constexpr int NE = 8192;    // codebook size
constexpr float DECAY = 0.99f;
constexpr float BETA  = 1.0f;
constexpr float EPS   = 1e-5f;
constexpr float LO_SCALE     = 4096.0f;        // 2^12: keeps f16 lo-part normal
constexpr float INV_LO_SCALE = 1.0f / 4096.0f;

// packed-screen quantization: u = (u32(s*65536 + 98304) << 13) | code
constexpr float QSCALE = 65536.0f;
constexpr float QOFF   = 98304.0f;

// distance-kernel geometry
constexpr int Q = 4;                       // code slices (grid.y)
constexpr int CODES_PER_Q = NE / Q;        // 2048
constexpr int TILE_C = 64;                 // codes per block-shared LDS tile
constexpr int TILES = CODES_PER_Q / TILE_C;// 32
constexpr int BZ = 128;                    // z rows per block (4 waves x 32 rows)
constexpr int NCAND = Q * 2;               // refine candidates per row (8)

// ---------------- ws layout (float units) ----------------
constexpr size_t WS_Z2    = 0;                            // NV x 256 f16 = NV*128 floats
constexpr size_t WS_E2    = WS_Z2 + (size_t)NV * 128;     // NE x 128 f16 (hi only); region NE*128 floats
constexpr size_t WS_EN2   = WS_E2 + (size_t)NE * 128;     // NE (fp32)
constexpr size_t WS_MINI2 = WS_EN2 + NE;                  // NV*NCAND (u32 packed)
// aliases over z2 region (z2 dead once k_dist finishes)
constexpr size_t WS_BINS  = WS_Z2;                        // NE
constexpr size_t WS_ESUM  = WS_BINS + NE;                 // NE*D
constexpr size_t WS_LPART = WS_ESUM + (size_t)NE * D;     // 4096

// ---------------- out layout (float units) ----------------
constexpr size_t OUT_ZQ   = 0;                         // NV*D
constexpr size_t OUT_LOSS = OUT_ZQ + (size_t)NV*D;     // 1
constexpr size_t OUT_IDX  = OUT_LOSS + 1;              // NV
constexpr size_t OUT_EMB  = OUT_IDX + NV;              // NE*D
constexpr size_t OUT_CS   = OUT_EMB + (size_t)NE*D;    // NE
constexpr size_t OUT_EAVG = OUT_CS + NE;               // NE*D

using half8  = __attribute__((ext_vector_type(8))) _Float16;
using half2v = __attribute__((ext_vector_type(2))) _Float16;
using f32x16 = __attribute__((ext_vector_type(16))) float;

__device__ inline float waveReduceSum(float v) {
    #pragma unroll
    for (int o = 32; o > 0; o >>= 1) v += __shfl_xor(v, o, 64);
    return v;
}
__device__ inline unsigned umin32(unsigned a, unsigned b) { return a < b ? a : b; }
__device__ inline unsigned umax32(unsigned a, unsigned b) { return a > b ? a : b; }

// async global->LDS, 16B per lane; LDS dest = wave-uniform base + lane*16 (linear)
__device__ inline void gload_lds16(const void* g, void* s) {
    __builtin_amdgcn_global_load_lds(
        (const __attribute__((address_space(1))) unsigned int*)g,
        (__attribute__((address_space(3))) unsigned int*)s, 16, 0, 0);
}

// ---------- fused prep: z rows (normalize + hi/lo split) and emb rows (hi-only + |e|^2) ----------
__global__ void k_prep(const float* __restrict__ z, const float* __restrict__ emb,
                       _Float16* __restrict__ z2, _Float16* __restrict__ e2h,
                       float* __restrict__ en2) {
    int tid = threadIdx.x;
    int l = tid & 63;
    int g = blockIdx.x * 4 + (tid >> 6);
    bool isZ = g < NV;
    int row = isZ ? g : g - NV;
    const float* src = isZ ? &z[(size_t)row * D] : &emb[(size_t)row * D];

    const float2 v = *reinterpret_cast<const float2*>(&src[l * 2]);
    float s = waveReduceSum(v.x * v.x + v.y * v.y);
    float x0 = v.x, x1 = v.y;
    if (isZ) {
        float inv = 1.0f / fmaxf(sqrtf(s), 1e-12f);
        x0 *= inv; x1 *= inv;
        _Float16 h0 = (_Float16)x0, h1 = (_Float16)x1;
        _Float16 l0 = (_Float16)((x0 - (float)h0) * LO_SCALE);
        _Float16 l1 = (_Float16)((x1 - (float)h1) * LO_SCALE);
        _Float16* zr = &z2[(size_t)row * 256];
        half2v hh = {h0, h1}, lv = {l0, l1};
        *reinterpret_cast<half2v*>(&zr[l * 2])       = hh;
        *reinterpret_cast<half2v*>(&zr[128 + l * 2]) = lv;
    } else {
        if (l == 0) en2[row] = s;   // bitwise = round-1 k_enorm2
        _Float16 h0 = (_Float16)x0, h1 = (_Float16)x1;
        half2v hh = {h0, h1};
        *reinterpret_cast<half2v*>(&e2h[(size_t)row * 128 + l * 2]) = hh;
    }
}

// ---------- MFMA 32x32x16 distance screen (R18: best-measured configuration) ----------
// 256 thr = 4 waves; wave owns 32 z rows. Block-shared 64-code tiles, TRIPLE-buffered
// via global_load_lds, prefetch depth 2. Per tile: raw s_barrier (execution sync, NO
// vmcnt drain) + issue stage(t+2) + counted s_waitcnt vmcnt(8) (own stage-t landed;
// the 8 newer loads stay in flight ACROSS the barrier - T4). Counted discipline:
// one-time vmcnt(0) after A/c0s loads keeps the outstanding queue = stage loads only
// (vmcnt retires in issue order); one-time lgkmcnt(0) makes c0s ds_writes visible at
// the first barrier; ds_reads complete before each wave's next barrier because MFMA
// consumed their results (auto-lgkmcnt). sched_barrier(0) pins ds_reads (rule 18).
// 2-term screen: dot ~= zh.eh + (zl.eh)/4096 (err ~2e-5; covered by top-2-per-slice +
// fp32 arbiter). 7-op packed-u32 top-2 epilogue.
// C/D: col=lane&31, row=(reg&3)+8*(reg>>2)+4*(lane>>5) (m74/m101-verified).
// Measured floor note (R17-R20): 81-85 us across 4 structural variants; latency-bound
// at the chip's immovable ~2 blocks/CU residency. This is the Pareto-best variant.
__global__ __launch_bounds__(256, 2) void k_dist(
        const _Float16* __restrict__ z2, const _Float16* __restrict__ e2h,
        const float* __restrict__ en2, unsigned* __restrict__ minI2) {
    __shared__ _Float16 eb[3][TILE_C * 128];   // 3 x 16 KB
    __shared__ float c0s[CODES_PER_Q];         // 8 KB

    const int tid = threadIdx.x;
    const int w  = tid >> 6;
    const int l  = tid & 63;
    const int cc = l & 31;      // A-row / B-col index (32-wide)
    const int gg = l >> 5;      // k-half group (0..1)
    const int zb = blockIdx.x * BZ;
    const int q  = blockIdx.y;
    const int cbase0 = q * CODES_PER_Q;

    // A fragments: a_h/a_l[kf] = z2[row][kf*16 + gg*8 ..+8] (hi), +128 (lo); kf=0..7
    half8 a_h[8], a_l[8];
    {
        const size_t row = (size_t)(zb + w * 32 + cc);
        #pragma unroll
        for (int kf = 0; kf < 8; ++kf) {
            a_h[kf] = *reinterpret_cast<const half8*>(&z2[row * 256 + kf * 16 + gg * 8]);
            a_l[kf] = *reinterpret_cast<const half8*>(&z2[row * 256 + 128 + kf * 16 + gg * 8]);
        }
    }

    // prequantized constant: c0 = |e|^2 * QSCALE + QOFF
    for (int i = tid; i < CODES_PER_Q; i += 256)
        c0s[i] = fmaf(en2[cbase0 + i], QSCALE, QOFF);

    // drain A/en2 loads + c0s ds_writes so the vmcnt queue = stage loads ONLY,
    // and this wave's c0s writes are complete before the first barrier.
    asm volatile("s_waitcnt vmcnt(0) lgkmcnt(0)" ::: "memory");

    // stage tile t: 1024 chunks; wave w load i covers chunk (w*4+i)*64 + l
    int soff[4];
    #pragma unroll
    for (int i = 0; i < 4; ++i) {
        int c = (w * 4 + i) * 64 + l;
        int code = c >> 4, slot = c & 15;
        soff[i] = code * 256 + ((slot ^ (code & 7)) * 16);
    }
    auto stage = [&](int b, int t) {
        const char* tbase = reinterpret_cast<const char*>(&e2h[(size_t)(cbase0 + t * TILE_C) * 128]);
        #pragma unroll
        for (int i = 0; i < 4; ++i)
            gload_lds16(tbase + soff[i], &eb[b][(size_t)(w * 4 + i) * 512]);
    };

    stage(0, 0);            // 4 outstanding
    stage(1, 1);            // 8 outstanding

    unsigned bU1[16], bU2[16];
    #pragma unroll
    for (int i = 0; i < 16; ++i) { bU1[i] = 0xFFFFFFFFu; bU2[i] = 0xFFFFFFFFu; }

    const int swz = cc & 7;      // read-side XOR (matches staged involution)

    int cur = 0;
    for (int t = 0; t < TILES; ++t) {
        // barrier: all waves done reading buf[(t-1)%3] (= target of stage(t+2));
        // raw s_barrier only - prefetch loads stay in flight across it.
        __builtin_amdgcn_s_barrier();
        if (t + 2 < TILES) {
            int nb = cur + 2; if (nb >= 3) nb -= 3;
            stage(nb, t + 2);                               // 12 outstanding
            asm volatile("s_waitcnt vmcnt(8)" ::: "memory");  // own stage-t landed
        } else if (t + 1 < TILES) {
            asm volatile("s_waitcnt vmcnt(4)" ::: "memory");
        } else {
            asm volatile("s_waitcnt vmcnt(0)" ::: "memory");
        }
        __builtin_amdgcn_sched_barrier(0);

        #pragma unroll
        for (int n = 0; n < 2; ++n) {          // colfrag: 32 codes each
            const char* rbase = reinterpret_cast<const char*>(&eb[cur][0])
                                + (n * 32 + cc) * 256;
            half8 b0 = *reinterpret_cast<const half8*>(rbase + (((0 * 2 + gg) ^ swz) * 16));
            half8 b1 = *reinterpret_cast<const half8*>(rbase + (((1 * 2 + gg) ^ swz) * 16));
            half8 b2 = *reinterpret_cast<const half8*>(rbase + (((2 * 2 + gg) ^ swz) * 16));
            half8 b3 = *reinterpret_cast<const half8*>(rbase + (((3 * 2 + gg) ^ swz) * 16));
            half8 b4 = *reinterpret_cast<const half8*>(rbase + (((4 * 2 + gg) ^ swz) * 16));
            half8 b5 = *reinterpret_cast<const half8*>(rbase + (((5 * 2 + gg) ^ swz) * 16));
            half8 b6 = *reinterpret_cast<const half8*>(rbase + (((6 * 2 + gg) ^ swz) * 16));
            half8 b7 = *reinterpret_cast<const half8*>(rbase + (((7 * 2 + gg) ^ swz) * 16));

            f32x16 accA{}, accB{};
            // 2 chains, interleaved (R16/R17-proven numerics); 16 MFMA per colfrag
            accA = __builtin_amdgcn_mfma_f32_32x32x16_f16(a_h[0], b0, accA, 0, 0, 0);
            accB = __builtin_amdgcn_mfma_f32_32x32x16_f16(a_l[0], b0, accB, 0, 0, 0);
            accA = __builtin_amdgcn_mfma_f32_32x32x16_f16(a_h[1], b1, accA, 0, 0, 0);
            accB = __builtin_amdgcn_mfma_f32_32x32x16_f16(a_l[1], b1, accB, 0, 0, 0);
            accA = __builtin_amdgcn_mfma_f32_32x32x16_f16(a_h[2], b2, accA, 0, 0, 0);
            accB = __builtin_amdgcn_mfma_f32_32x32x16_f16(a_l[2], b2, accB, 0, 0, 0);
            accA = __builtin_amdgcn_mfma_f32_32x32x16_f16(a_h[3], b3, accA, 0, 0, 0);
            accB = __builtin_amdgcn_mfma_f32_32x32x16_f16(a_l[3], b3, accB, 0, 0, 0);
            accA = __builtin_amdgcn_mfma_f32_32x32x16_f16(a_h[4], b4, accA, 0, 0, 0);
            accB = __builtin_amdgcn_mfma_f32_32x32x16_f16(a_l[4], b4, accB, 0, 0, 0);
            accA = __builtin_amdgcn_mfma_f32_32x32x16_f16(a_h[5], b5, accA, 0, 0, 0);
            accB = __builtin_amdgcn_mfma_f32_32x32x16_f16(a_l[5], b5, accB, 0, 0, 0);
            accA = __builtin_amdgcn_mfma_f32_32x32x16_f16(a_h[6], b6, accA, 0, 0, 0);
            accB = __builtin_amdgcn_mfma_f32_32x32x16_f16(a_l[6], b6, accB, 0, 0, 0);
            accA = __builtin_amdgcn_mfma_f32_32x32x16_f16(a_h[7], b7, accA, 0, 0, 0);
            accB = __builtin_amdgcn_mfma_f32_32x32x16_f16(a_l[7], b7, accB, 0, 0, 0);

            const unsigned code = (unsigned)(cbase0 + t * TILE_C + n * 32 + cc);
            const float c0 = c0s[t * TILE_C + n * 32 + cc];
            #pragma unroll
            for (int r = 0; r < 16; ++r) {
                // 7-op insert: fma, fma, cvt, lshl_or, max, min, min
                float tq = fmaf(-2.0f * QSCALE, accA[r],
                                fmaf(-2.0f * QSCALE * INV_LO_SCALE, accB[r], c0));
                unsigned u = ((unsigned)tq << 13) | code;
                unsigned m1 = bU1[r];
                bU2[r] = umin32(umax32(u, m1), bU2[r]);   // second-min (med3 pattern)
                bU1[r] = umin32(u, m1);
            }
        }
        ++cur; if (cur >= 3) cur -= 3;
    }

    // cross-lane top-2 merge over the 32 cc lanes (disjoint code sets; u unique)
    #pragma unroll
    for (int r = 0; r < 16; ++r) {
        unsigned u1 = bU1[r], u2 = bU2[r];
        #pragma unroll
        for (int m = 1; m < 32; m <<= 1) {
            unsigned o1 = (unsigned)__shfl_xor((int)u1, m, 64);
            unsigned o2 = (unsigned)__shfl_xor((int)u2, m, 64);
            unsigned hi = umax32(u1, o1);
            u1 = umin32(u1, o1);
            u2 = umin32(umin32(u2, o2), hi);
        }
        if (cc == 0) {
            // C/D: row = (r&3) + 8*(r>>2) + 4*gg
            int zrow = zb + w * 32 + (r & 3) + 8 * (r >> 2) + 4 * gg;
            size_t o = ((size_t)zrow * Q + q) * 2;
            minI2[o] = u1; minI2[o + 1] = u2;
        }
    }
}

// ---------- fp32-replica refine over 8 candidates (LDS-staged rows) + gather + loss + segsums ----------
__global__ void k_gather(const float* __restrict__ z, const float* __restrict__ emb,
                         const float* __restrict__ en2, const unsigned* __restrict__ minI2,
                         float* __restrict__ outZq, float* __restrict__ outIdx,
                         float* __restrict__ bins, float* __restrict__ esum,
                         float* __restrict__ lossPart) {
    __shared__ float zsh[4][128];
    __shared__ float ecs[4][NCAND][132];    // +4 pad: 8 chain-lanes hit distinct banks
    int tid = threadIdx.x;
    int wave = tid >> 6, lane = tid & 63;
    int zr = blockIdx.x * 4 + wave;

    // zn exactly as round-1 k_norm_z (fp32 butterfly, same ops)
    const float2 zv = *reinterpret_cast<const float2*>(&z[(size_t)zr * D + lane * 2]);
    float s = waveReduceSum(zv.x * zv.x + zv.y * zv.y);
    float inv = 1.0f / fmaxf(sqrtf(s), 1e-12f);
    float znx = zv.x * inv, zny = zv.y * inv;
    zsh[wave][lane * 2]     = znx;
    zsh[wave][lane * 2 + 1] = zny;

    // candidate codes + coalesced staging of the 8 rows (values bit-identical;
    // the arbiter chain below is unchanged). All per-wave LDS: no block barrier.
    int ci = 0x7fffffff;
    if (lane < NCAND) ci = (int)(minI2[(size_t)zr * NCAND + lane] & 8191u);
    #pragma unroll
    for (int c = 0; c < NCAND; ++c) {
        int cc_ = __shfl(ci, c, 64);
        const float2 ev = *reinterpret_cast<const float2*>(&emb[(size_t)cc_ * D + lane * 2]);
        ecs[wave][c][lane * 2]     = ev.x;
        ecs[wave][c][lane * 2 + 1] = ev.y;
    }

    // 8 lanes re-score with the proven fp32 arbiter arithmetic:
    // sequential fmaf chain k=0..127, then s = fmaf(-2, dot, en2[c]).
    float cv = 3.4e38f;
    if (lane < NCAND) {
        float dot = 0.0f;
        #pragma unroll 8
        for (int k = 0; k < 128; ++k) dot = fmaf(zsh[wave][k], ecs[wave][lane][k], dot);
        cv = fmaf(-2.0f, dot, en2[ci]);
    }
    float bv = cv; int bi = ci;
    #pragma unroll
    for (int m = 1; m < NCAND; m <<= 1) {
        float ov = __shfl_xor(bv, m, 64);
        int   oi = __shfl_xor(bi, m, 64);
        if (ov < bv || (ov == bv && oi < bi)) { bv = ov; bi = oi; }
    }
    bi = __shfl(bi, 0, 64);    // broadcast winner to all 64 lanes
    if (lane == 0) outIdx[zr] = (float)bi;

    float2 e = *reinterpret_cast<const float2*>(&emb[(size_t)bi * D + lane * 2]);
    *reinterpret_cast<float2*>(&outZq[(size_t)zr * D + lane * 2]) = e;

    float dx = e.x - znx, dy = e.y - zny;
    float ls = waveReduceSum(dx * dx + dy * dy);

    if (lane == 0) atomicAdd(&bins[bi], 1.0f);
    atomicAdd(&esum[(size_t)bi * D + lane * 2 + 0], znx);
    atomicAdd(&esum[(size_t)bi * D + lane * 2 + 1], zny);

    __shared__ float part[4];
    if (lane == 0) part[wave] = ls;
    __syncthreads();
    if (tid == 0) lossPart[blockIdx.x] = (part[0] + part[1]) + (part[2] + part[3]);
}

// ---------- per-code EMA update + renormalize; block 0 also reduces the loss ----------
__global__ void k_codebook(const float* __restrict__ emb, const float* __restrict__ csz,
                           const float* __restrict__ eavg, const float* __restrict__ bins,
                           const float* __restrict__ esum, const float* __restrict__ lossPart,
                           float* __restrict__ outEmb, float* __restrict__ outCs,
                           float* __restrict__ outEavg, float* __restrict__ outLoss) {
    int tid = threadIdx.x;
    int wave = tid >> 6, lane = tid & 63;
    int n = blockIdx.x * 4 + wave;

    if (blockIdx.x == 0) {               // fold former k_loss here (block-uniform branch)
        float s = 0.0f;
        for (int i = tid; i < 4096; i += 256) s += lossPart[i];
        s = waveReduceSum(s);
        __shared__ float p[4];
        if ((tid & 63) == 0) p[tid >> 6] = s;
        __syncthreads();
        if (tid == 0) outLoss[0] = BETA * ((p[0] + p[1]) + (p[2] + p[3])) / (float)((size_t)NV * D);
    }

    float b = bins[n];
    if (lane == 0) outCs[n] = csz[n] * DECAY + (1.0f - DECAY) * b;

    float2 es = *reinterpret_cast<const float2*>(&esum[(size_t)n * D + lane * 2]);
    float invb = 1.0f / (b + EPS);
    float mx = es.x * invb, my = es.y * invb;
    float ss = waveReduceSum(mx * mx + my * my);
    float invn = 1.0f / fmaxf(sqrtf(ss), 1e-12f);

    float2 er = *reinterpret_cast<const float2*>(&emb[(size_t)n * D + lane * 2]);
    float enx = (b == 0.0f) ? er.x : mx * invn;
    float eny = (b == 0.0f) ? er.y : my * invn;

    float2 ea = *reinterpret_cast<const float2*>(&eavg[(size_t)n * D + lane * 2]);
    float nax = ea.x * DECAY + (1.0f - DECAY) * enx;
    float nay = ea.y * DECAY + (1.0f - DECAY) * eny;
    float2 no; no.x = nax; no.y = nay;
    *reinterpret_cast<float2*>(&outEavg[(size_t)n * D + lane * 2]) = no;

    float ss2 = waveReduceSum(nax * nax + nay * nay);
    float inv2 = 1.0f / fmaxf(sqrtf(ss2), 1e-12f);
    float2 ne; ne.x = nax * inv2; ne.y = nay * inv2;
    *reinterpret_cast<float2*>(&outEmb[(size_t)n * D + lane * 2]) = ne;
}

extern "C" void kernel_launch(void* const* d_in, const int* in_sizes, int n_in,
                              void* d_out, int out_size, void* d_ws, size_t ws_size,
                              hipStream_t stream) {
    (void)in_sizes; (void)n_in; (void)out_size; (void)ws_size;
    const float* z    = (const float*)d_in[0];
    const float* emb  = (const float*)d_in[1];
    const float* csz  = (const float*)d_in[2];
    const float* eavg = (const float*)d_in[3];
    float* out = (float*)d_out;
    float* ws  = (float*)d_ws;

    _Float16* z2   = (_Float16*)(ws + WS_Z2);
    _Float16* e2h  = (_Float16*)(ws + WS_E2);
    float*    en2  = ws + WS_EN2;
    unsigned* minI2 = (unsigned*)(ws + WS_MINI2);
    float*  bins   = ws + WS_BINS;
    float*  esum   = ws + WS_ESUM;
    float*  lpart  = ws + WS_LPART;

    k_prep<<<(NV + NE) / 4, 256, 0, stream>>>(z, emb, z2, e2h, en2);
    k_dist<<<dim3(NV / BZ, Q), 256, 0, stream>>>(z2, e2h, en2, minI2);
    // bins+esum zeroing must follow k_dist (they alias the z2 region)
    hipMemsetAsync(bins, 0, ((size_t)NE + (size_t)NE * D) * sizeof(float), stream);
    k_gather<<<NV / 4, 256, 0, stream>>>(z, emb, en2, minI2,
                                         out + OUT_ZQ, out + OUT_IDX, bins, esum, lpart);
    k_codebook<<<NE / 4, 256, 0, stream>>>(emb, csz, eavg, bins, esum, lpart,
                                           out + OUT_EMB, out + OUT_CS, out + OUT_EAVG,
                                           out + OUT_LOSS);
}